// Round 5
// baseline (217.829 us; speedup 1.0000x reference)
//
#include <hip/hip_runtime.h>
#include <hip/hip_bf16.h>
#include <stdint.h>

// LocalAttention: B=16, N=1024 (32x32 grid), C=1024, H=16, D=64.
// cvt->bf16 (fused) ; GEMM1 qkv=x@w_qkv^T (256^2 8-wave bf16 MFMA, m201-style
// 4-phase interleave, spread 2-deep staging, counted vmcnt, T2 swizzle) ;
// local 3x3 window attention ; GEMM2 out=attn@w_proj^T+b. Workspace ~176.2 MB.

typedef __bf16 bf16;
typedef __bf16 bf16x4_t __attribute__((ext_vector_type(4)));
typedef __bf16 bf16x8_t __attribute__((ext_vector_type(8)));
typedef float f32x4_t __attribute__((ext_vector_type(4)));

static __device__ __forceinline__ void gload_lds16(const void* g, void* l) {
  __builtin_amdgcn_global_load_lds((__attribute__((address_space(1))) void*)g,
                                   (__attribute__((address_space(3))) void*)l,
                                   16, 0, 0);
}

// raw s_barrier with compile-time memory fences (no vmcnt/lgkm drain)
static __device__ __forceinline__ void block_barrier() {
  asm volatile("" ::: "memory");
  __builtin_amdgcn_s_barrier();
  asm volatile("" ::: "memory");
}

// ---------------- fused f32 -> bf16 conversion (x, w_qkv, w_proj) --------------
__global__ void cvt_all(const float* __restrict__ x, const float* __restrict__ wq,
                        const float* __restrict__ wp, bf16* __restrict__ xb,
                        bf16* __restrict__ wqb, bf16* __restrict__ wpb) {
  constexpr int NX = 4194304, NWQ = 786432;          // float4 counts
  int i = blockIdx.x * blockDim.x + threadIdx.x;     // grid exactly covers total
  const float* src; bf16* dst; int off;
  if (i < NX)            { src = x;  dst = xb;  off = i; }
  else if (i < NX + NWQ) { src = wq; dst = wqb; off = i - NX; }
  else                   { src = wp; dst = wpb; off = i - (NX + NWQ); }
  float4 v = reinterpret_cast<const float4*>(src)[off];
  bf16x4_t o;
  o[0] = (bf16)v.x; o[1] = (bf16)v.y; o[2] = (bf16)v.z; o[3] = (bf16)v.w;
  reinterpret_cast<bf16x4_t*>(dst)[off] = o;
}

// ---------------- 256x256 8-wave bf16 GEMM, C = A @ B^T ------------------------
// A: [M][K], Bm: [N][K] (both K-major). 512 threads = 8 waves (2M x 4N).
// LDS 128 KiB: 2 slots x (A 256x64 + B 256x64) bf16, T2-swizzled.
// 4 phases/K-tile, zig-zag quadrants (00,01,11,10), each fragment read once.
// Hazard certification for spread 2-deep staging into the CURRENTLY-READ slot:
//   all B reads (b0,b1) issued in ph0/ph1, drained by each wave's lgkmcnt(0)
//   before ph1's final barrier  -> stage B of tile kt+2 in ph2;
//   all A reads (a0,a1) drained before ph2's final barrier -> stage A in ph3.
// End of tile: counted vmcnt(8) (tile kt+2's 8 loads stay in flight) + barrier.
template<int OUT_BF16>
__global__ __launch_bounds__(512, 2)
void gemm256(const bf16* __restrict__ A, const bf16* __restrict__ Bm,
             void* __restrict__ Cout, const float* __restrict__ bias,
             int M, int N, int K) {
  extern __shared__ __align__(16) bf16 lds[];

  const int tid = threadIdx.x;
  const int w = tid >> 6, lane = tid & 63;
  const int fr = lane & 15, g = lane >> 4;
  const int wr = w >> 2, wc = w & 3;          // wave grid 2 x 4

  // T1: XCD-aware bijective swizzle (nwg % 8 == 0 for both call sites)
  const int nwg = gridDim.x * gridDim.y;
  int lid = blockIdx.y * gridDim.x + blockIdx.x;
  lid = (lid & 7) * (nwg >> 3) + (lid >> 3);
  const int bx = lid % gridDim.x, by = lid / gridDim.x;
  const int row0 = by * 256, col0 = bx * 256;

  const bf16* Ag = A + (size_t)row0 * K;
  const bf16* Bg = Bm + (size_t)col0 * K;
  const int rsub = tid >> 3;                               // 0..63
  const int csw  = ((tid & 7) * 8) ^ ((rsub & 7) << 3);    // inverse-swizzled src col
  const int nkt  = K >> 6;

  f32x4_t acc[8][4] = {};

  auto stageA = [&](int kt, int slot) {
    const int kb = kt << 6;
    bf16* sl = lds + slot * 32768;
#pragma unroll
    for (int n = 0; n < 4; ++n)
      gload_lds16(Ag + (size_t)(rsub + n * 64) * K + kb + csw,
                  sl + n * 4096 + w * 512);
  };
  auto stageB = [&](int kt, int slot) {
    const int kb = kt << 6;
    bf16* sl = lds + slot * 32768 + 16384;
#pragma unroll
    for (int n = 0; n < 4; ++n)
      gload_lds16(Bg + (size_t)(rsub + n * 64) * K + kb + csw,
                  sl + n * 4096 + w * 512);
  };

  const int axor = (fr & 7) << 4;   // T2 read-side XOR (lane-constant)

  // prologue: tiles 0,1 fully staged; wait tile 0 (tile 1's 8 stay in flight)
  stageB(0, 0); stageA(0, 0);
  stageB(1, 1); stageA(1, 1);
  asm volatile("s_waitcnt vmcnt(8)" ::: "memory");
  block_barrier();

  for (int kt = 0; kt < nkt; ++kt) {
    const char* cA = reinterpret_cast<const char*>(lds + (kt & 1) * 32768);
    const char* cB = cA + 32768;
    const bool pf = (kt + 2 < nkt);

    bf16x8_t a0[4][2], a1[4][2], b0[2][2], b1[2][2];

    auto lda = [&](bf16x8_t (&dst)[4][2], int q) {
#pragma unroll
      for (int i = 0; i < 4; ++i) {
        const int row = wr * 128 + (q * 4 + i) * 16 + fr;
#pragma unroll
        for (int kh = 0; kh < 2; ++kh) {
          const int bo = (row << 7) + (((kh << 6) + (g << 4)) ^ axor);
          dst[i][kh] = *reinterpret_cast<const bf16x8_t*>(cA + bo);
        }
      }
    };
    auto ldb = [&](bf16x8_t (&dst)[2][2], int q) {
#pragma unroll
      for (int j = 0; j < 2; ++j) {
        const int row = wc * 64 + (q * 2 + j) * 16 + fr;
#pragma unroll
        for (int kh = 0; kh < 2; ++kh) {
          const int bo = (row << 7) + (((kh << 6) + (g << 4)) ^ axor);
          dst[j][kh] = *reinterpret_cast<const bf16x8_t*>(cB + bo);
        }
      }
    };
    auto mfma16 = [&](bf16x8_t (&af)[4][2], bf16x8_t (&bf_)[2][2], int mi0, int nj0) {
      __builtin_amdgcn_s_setprio(1);
#pragma unroll
      for (int i = 0; i < 4; ++i)
#pragma unroll
        for (int j = 0; j < 2; ++j)
#pragma unroll
          for (int kh = 0; kh < 2; ++kh)
            acc[mi0 + i][nj0 + j] = __builtin_amdgcn_mfma_f32_16x16x32_bf16(
                af[i][kh], bf_[j][kh], acc[mi0 + i][nj0 + j], 0, 0, 0);
      __builtin_amdgcn_s_setprio(0);
    };

    // ---- ph0: read a0(8) + b0(4); MFMA quad (0,0) ----
    lda(a0, 0); ldb(b0, 0);
    asm volatile("s_waitcnt lgkmcnt(8)" ::: "memory");
    block_barrier();
    asm volatile("s_waitcnt lgkmcnt(0)" ::: "memory");
    __builtin_amdgcn_sched_barrier(0);
    mfma16(a0, b0, 0, 0);
    block_barrier();

    // ---- ph1: read b1(4); MFMA quad (0,1) ----
    ldb(b1, 1);
    block_barrier();
    asm volatile("s_waitcnt lgkmcnt(0)" ::: "memory");
    __builtin_amdgcn_sched_barrier(0);
    mfma16(a0, b1, 0, 2);
    block_barrier();     // certifies: ALL B reads of this slot complete chip-wide

    // ---- ph2: read a1(8); stage B of tile kt+2; MFMA quad (1,1) ----
    lda(a1, 1);
    if (pf) stageB(kt + 2, kt & 1);
    block_barrier();
    asm volatile("s_waitcnt lgkmcnt(0)" ::: "memory");
    __builtin_amdgcn_sched_barrier(0);
    mfma16(a1, b1, 4, 2);
    block_barrier();     // certifies: ALL A reads of this slot complete chip-wide

    // ---- ph3: stage A of tile kt+2; MFMA quad (1,0); counted vmcnt ----
    if (pf) stageA(kt + 2, kt & 1);
    block_barrier();
    __builtin_amdgcn_sched_barrier(0);
    mfma16(a1, b0, 4, 0);
    if (pf) {
      asm volatile("s_waitcnt vmcnt(8)" ::: "memory");   // tile kt+1 landed
    } else {
      asm volatile("s_waitcnt vmcnt(0)" ::: "memory");   // tail drain (cheap)
    }
    block_barrier();
  }

  // epilogue: D row = g*4+r (M), col = fr (N) per verified m89 layout
#pragma unroll
  for (int fm = 0; fm < 8; ++fm) {
    const int rbase = row0 + wr * 128 + fm * 16 + g * 4;
#pragma unroll
    for (int fn = 0; fn < 4; ++fn) {
      const int col = col0 + wc * 64 + fn * 16 + fr;
#pragma unroll
      for (int r = 0; r < 4; ++r) {
        const size_t idx = (size_t)(rbase + r) * N + col;
        if constexpr (OUT_BF16) {
          reinterpret_cast<bf16*>(Cout)[idx] = (bf16)acc[fm][fn][r];
        } else {
          reinterpret_cast<float*>(Cout)[idx] = acc[fm][fn][r] + bias[col];
        }
      }
    }
  }
}

// ---------------- local 3x3 window attention -----------------------------------
// qkv: [B*N][3072] bf16 (q|k|v, head h at h*64). out: [B*N][1024] bf16.
// 8 tokens per wave; 8 lanes per token, each lane owns an 8-elem d-chunk (16B).
__global__ __launch_bounds__(256)
void local_attn(const bf16* __restrict__ qkv, bf16* __restrict__ outp) {
  const int tid  = threadIdx.x;
  const int wave = tid >> 6, lane = tid & 63;
  const int tsub = lane >> 3, ch = lane & 7;
  const int gt = (blockIdx.x * 4 + wave) * 8 + tsub;
  const int i  = gt & 1023;
  const int bh = gt >> 10;
  const int h  = bh & 15, b = bh >> 4;
  const int r  = i >> 5, c = i & 31;

  const bf16* base = qkv + (size_t)(b * 1024) * 3072 + h * 64 + ch * 8;

  bf16x8_t qv = *reinterpret_cast<const bf16x8_t*>(base + (size_t)i * 3072);
  float qf[8];
#pragma unroll
  for (int e = 0; e < 8; ++e) qf[e] = (float)qv[e];

  float s[9];
  bool valid[9];
#pragma unroll
  for (int dr = -1; dr <= 1; ++dr) {
#pragma unroll
    for (int dc = -1; dc <= 1; ++dc) {
      const int idx = (dr + 1) * 3 + (dc + 1);
      const int rr = r + dr, cc = c + dc;
      valid[idx] = (rr >= 0 && rr < 32 && cc >= 0 && cc < 32);
      float sv = -1e30f;
      if (valid[idx]) {
        const int j = rr * 32 + cc;
        bf16x8_t kv = *reinterpret_cast<const bf16x8_t*>(base + (size_t)j * 3072 + 1024);
        float ps = 0.f;
#pragma unroll
        for (int e = 0; e < 8; ++e) ps += qf[e] * (float)kv[e];
        ps += __shfl_xor(ps, 1);
        ps += __shfl_xor(ps, 2);
        ps += __shfl_xor(ps, 4);
        sv = ps * 0.125f;
      }
      s[idx] = sv;
    }
  }

  float mx = s[0];
#pragma unroll
  for (int t = 1; t < 9; ++t) mx = fmaxf(mx, s[t]);

  float p[9], denom = 0.f;
#pragma unroll
  for (int t = 0; t < 9; ++t) {
    p[t] = valid[t] ? __expf(s[t] - mx) : 0.f;
    denom += p[t];
  }

  float o[8] = {};
#pragma unroll
  for (int dr = -1; dr <= 1; ++dr) {
#pragma unroll
    for (int dc = -1; dc <= 1; ++dc) {
      const int idx = (dr + 1) * 3 + (dc + 1);
      if (valid[idx]) {
        const int j = (r + dr) * 32 + (c + dc);
        bf16x8_t vv = *reinterpret_cast<const bf16x8_t*>(base + (size_t)j * 3072 + 2048);
        const float pw = p[idx];
#pragma unroll
        for (int e = 0; e < 8; ++e) o[e] += pw * (float)vv[e];
      }
    }
  }

  const float inv = 1.f / denom;
  bf16x8_t ov;
#pragma unroll
  for (int e = 0; e < 8; ++e) ov[e] = (bf16)(o[e] * inv);
  *reinterpret_cast<bf16x8_t*>(outp + (size_t)(b * 1024 + i) * 1024 + h * 64 + ch * 8) = ov;
}

extern "C" void kernel_launch(void* const* d_in, const int* in_sizes, int n_in,
                              void* d_out, int out_size, void* d_ws, size_t ws_size,
                              hipStream_t stream) {
  const float* x      = (const float*)d_in[0];
  const float* w_qkv  = (const float*)d_in[1];
  const float* w_proj = (const float*)d_in[2];
  const float* b_proj = (const float*)d_in[3];
  float* out = (float*)d_out;

  const size_t nx   = (size_t)16384 * 1024;
  const size_t nwq  = (size_t)3072 * 1024;
  const size_t nwp  = (size_t)1024 * 1024;
  const size_t nqkv = (size_t)16384 * 3072;

  bf16* x_bf  = (bf16*)d_ws;
  bf16* wq_bf = x_bf + nx;
  bf16* wp_bf = wq_bf + nwq;
  bf16* qkv   = wp_bf + nwp;
  bf16* attn  = qkv + nqkv;

  (void)hipFuncSetAttribute((const void*)&gemm256<1>,
                            hipFuncAttributeMaxDynamicSharedMemorySize, 131072);
  (void)hipFuncSetAttribute((const void*)&gemm256<0>,
                            hipFuncAttributeMaxDynamicSharedMemorySize, 131072);

  // fused cvt: (nx+nwq+nwp)/4 float4s = 5242880 -> 20480 blocks x 256
  cvt_all<<<20480, 256, 0, stream>>>(x, w_qkv, w_proj, x_bf, wq_bf, wp_bf);

  // qkv = x @ w_qkv^T : M=16384, N=3072, K=1024 ; grid 12x64 = 768 (%8==0)
  gemm256<1><<<dim3(3072 / 256, 16384 / 256), 512, 131072, stream>>>(
      x_bf, wq_bf, qkv, nullptr, 16384, 3072, 1024);

  // local window attention: 262144 tokens, 32 tokens/block
  local_attn<<<8192, 256, 0, stream>>>(qkv, attn);

  // out = attn @ w_proj^T + b : M=16384, N=1024, K=1024 ; grid 4x64 = 256
  gemm256<0><<<dim3(1024 / 256, 16384 / 256), 512, 131072, stream>>>(
      attn, wp_bf, out, b_proj, 16384, 1024, 1024);
}